// Round 1
// baseline (489.693 us; speedup 1.0000x reference)
//
#include <hip/hip_runtime.h>
#include <hip/hip_bf16.h>

// BlockSparseLinear: y = x @ W^T + b
// x: [8192, 4096] fp32; weight: [1024, 64, 64] fp32 (nz = rb*16+kb contiguous,
// row_idx = repeat(arange(64),16) deterministic); bias: [4096] fp32.
// y[t, rb*64+o] = sum_kb sum_j x[t, col_idx[rb*16+kb]*64+j] * w[rb*16+kb][o][j] + bias
//
// Strategy: bf16 MFMA (16x16x32), 256-token x 64-outcol tile per workgroup,
// fp32->bf16 conversion during LDS staging. LDS ld=72 (+8 pad keeps 16B align,
// 4-bank row shift -> only 2-way conflict which is free).

#define NTHREADS 256
#define TM 256          // tokens per workgroup tile
#define KNZ 16          // nonzero col-blocks per row-block
#define XS_LD 72        // padded LDS leading dim (elements)
#define WS_LD 72

typedef __attribute__((ext_vector_type(8))) short short8;   // bf16 x8 MFMA frag
typedef __attribute__((ext_vector_type(4))) float floatx4;

// round-to-nearest-even fp32 -> bf16 (inputs are finite gaussians; no NaN path)
__device__ __forceinline__ unsigned short f2bf(float f) {
    unsigned u = __float_as_uint(f);
    u += 0x7fffu + ((u >> 16) & 1u);
    return (unsigned short)(u >> 16);
}

__global__ __launch_bounds__(NTHREADS)
void bsl_mfma_kernel(const float* __restrict__ x,
                     const float* __restrict__ w,
                     const float* __restrict__ bias,
                     const int* __restrict__ col_idx,
                     float* __restrict__ out)
{
    __shared__ unsigned short Xs[TM * XS_LD];   // 256x72 bf16 = 36 KB
    __shared__ unsigned short Ws[64 * WS_LD];   // 64x72 bf16 = 9 KB

    const int rb   = blockIdx.x;     // output row-block 0..63
    const int tt   = blockIdx.y;     // token tile
    const int tid  = threadIdx.x;
    const int lane = tid & 63;
    const int wv   = tid >> 6;       // wave 0..3 -> token sub-tile
    const int l15  = lane & 15;
    const int l4   = lane >> 4;      // 0..3
    const int tok0 = tt * TM;

    floatx4 acc[4][4];               // wave: 64 tokens x 64 outcols = 4x4 16x16 tiles
    #pragma unroll
    for (int i = 0; i < 4; ++i)
        #pragma unroll
        for (int j = 0; j < 4; ++j)
            acc[i][j] = (floatx4){0.f, 0.f, 0.f, 0.f};

    for (int kb = 0; kb < KNZ; ++kb) {
        const int nz = rb * KNZ + kb;
        const int cb = col_idx[nz];
        const float* xsrc = x + (size_t)tok0 * 4096 + (size_t)cb * 64;
        const float* wsrc = w + (size_t)nz * 4096;

        __syncthreads();   // previous compute phase done before overwriting LDS

        // Stage X tile: 256 rows x 64 cols fp32 -> bf16. 4096 float4, 16/thread.
        #pragma unroll
        for (int i = 0; i < 16; ++i) {
            int f   = i * NTHREADS + tid;
            int row = f >> 4;          // 16 float4 per row of 64 floats
            int c4  = f & 15;
            floatx4 v = *(const floatx4*)(xsrc + (size_t)row * 4096 + c4 * 4);
            ushort4 p;
            p.x = f2bf(v.x); p.y = f2bf(v.y); p.z = f2bf(v.z); p.w = f2bf(v.w);
            *(ushort4*)&Xs[row * XS_LD + c4 * 4] = p;
        }
        // Stage W block: 64x64 fp32 -> bf16. 1024 float4, 4/thread.
        #pragma unroll
        for (int i = 0; i < 4; ++i) {
            int f   = i * NTHREADS + tid;
            int row = f >> 4;
            int c4  = f & 15;
            floatx4 v = *(const floatx4*)(wsrc + row * 64 + c4 * 4);
            ushort4 p;
            p.x = f2bf(v.x); p.y = f2bf(v.y); p.z = f2bf(v.z); p.w = f2bf(v.w);
            *(ushort4*)&Ws[row * WS_LD + c4 * 4] = p;
        }

        __syncthreads();   // staging visible to all waves

        // Compute: K=64 block as two k-steps of 32.
        #pragma unroll
        for (int ks = 0; ks < 2; ++ks) {
            const int k0 = ks * 32 + l4 * 8;
            short8 a[4], b[4];
            #pragma unroll
            for (int mt = 0; mt < 4; ++mt)
                a[mt] = *(const short8*)&Xs[(wv * 64 + mt * 16 + l15) * XS_LD + k0];
            #pragma unroll
            for (int nt = 0; nt < 4; ++nt)
                b[nt] = *(const short8*)&Ws[(nt * 16 + l15) * WS_LD + k0];
            #pragma unroll
            for (int mt = 0; mt < 4; ++mt)
                #pragma unroll
                for (int nt = 0; nt < 4; ++nt)
                    acc[mt][nt] = __builtin_amdgcn_mfma_f32_16x16x32_bf16(
                        a[mt], b[nt], acc[mt][nt], 0, 0, 0);
        }
    }

    // Epilogue: C/D layout col = lane&15, row = (lane>>4)*4 + reg. Add bias, store fp32.
    const int ocol0 = rb * 64;
    #pragma unroll
    for (int nt = 0; nt < 4; ++nt) {
        const int col = ocol0 + nt * 16 + l15;
        const float bv = bias[col];
        #pragma unroll
        for (int mt = 0; mt < 4; ++mt) {
            const size_t trow = (size_t)tok0 + wv * 64 + mt * 16 + l4 * 4;
            float* op = out + trow * 4096 + col;
            #pragma unroll
            for (int r = 0; r < 4; ++r)
                op[(size_t)r * 4096] = acc[mt][nt][r] + bv;
        }
    }
}

extern "C" void kernel_launch(void* const* d_in, const int* in_sizes, int n_in,
                              void* d_out, int out_size, void* d_ws, size_t ws_size,
                              hipStream_t stream) {
    const float* x       = (const float*)d_in[0];
    const float* w       = (const float*)d_in[1];
    const float* bias    = (const float*)d_in[2];
    // d_in[3] = row_idx (unused: deterministic repeat(arange(64),16) layout)
    const int*   col_idx = (const int*)d_in[4];
    float*       out     = (float*)d_out;

    const int n_tok = in_sizes[0] / 4096;      // 8192
    dim3 grid(64, n_tok / TM);                 // rb fastest -> wgs sharing an x-slab co-run
    bsl_mfma_kernel<<<grid, NTHREADS, 0, stream>>>(x, w, bias, col_idx, out);
}

// Round 2
// 348.041 us; speedup vs baseline: 1.4070x; 1.4070x over previous
//
#include <hip/hip_runtime.h>
#include <hip/hip_bf16.h>

// BlockSparseLinear: y = x @ W^T + b
// Round 2: pre-convert x,w to bf16 in d_ws (working set 72 MB -> L3-resident),
// then bf16 MFMA GEMM. XCD-aware swizzle keeps each token-tile's x slab (2 MB)
// hot in one XCD's L2 across all 64 row-blocks.

#define NTHREADS 256
#define TM 256          // tokens per workgroup tile
#define KNZ 16          // nonzero col-blocks per row-block
#define XS_LD 72        // padded LDS leading dim: 144 B stride -> 4-bank shift, 2-way=free
#define WS_LD 72

typedef __attribute__((ext_vector_type(8))) short short8;    // bf16 x8 (16 B)
typedef __attribute__((ext_vector_type(4))) float floatx4;

__device__ __forceinline__ unsigned short f2bf(float f) {
    unsigned u = __float_as_uint(f);
    u += 0x7fffu + ((u >> 16) & 1u);
    return (unsigned short)(u >> 16);
}

// ---- Kernel 1: fp32 -> bf16 conversion (x then w), 8 elems/thread ----
__global__ __launch_bounds__(NTHREADS)
void cvt_kernel(const float* __restrict__ x, const float* __restrict__ w,
                unsigned short* __restrict__ xb, unsigned short* __restrict__ wb,
                int n_x8, int n_w8)   // counts of 8-element groups
{
    int g = blockIdx.x * NTHREADS + threadIdx.x;
    const float* src;
    unsigned short* dst;
    if (g < n_x8) { src = x + (size_t)g * 8; dst = xb + (size_t)g * 8; }
    else {
        int h = g - n_x8;
        if (h >= n_w8) return;
        src = w + (size_t)h * 8; dst = wb + (size_t)h * 8;
    }
    floatx4 v0 = *(const floatx4*)(src);
    floatx4 v1 = *(const floatx4*)(src + 4);
    union { ushort4 u4[2]; short8 s8; } p;
    p.u4[0].x = f2bf(v0.x); p.u4[0].y = f2bf(v0.y);
    p.u4[0].z = f2bf(v0.z); p.u4[0].w = f2bf(v0.w);
    p.u4[1].x = f2bf(v1.x); p.u4[1].y = f2bf(v1.y);
    p.u4[1].z = f2bf(v1.z); p.u4[1].w = f2bf(v1.w);
    *(short8*)dst = p.s8;
}

// ---- Kernel 2: bf16 MFMA GEMM ----
__global__ __launch_bounds__(NTHREADS)
void bsl_mfma_bf16_kernel(const unsigned short* __restrict__ xb,
                          const unsigned short* __restrict__ wb,
                          const float* __restrict__ bias,
                          const int* __restrict__ col_idx,
                          float* __restrict__ out,
                          int n_tiles)   // token tiles (32)
{
    __shared__ unsigned short Xs[TM * XS_LD];   // 36 KB
    __shared__ unsigned short Ws[64 * WS_LD];   // 9 KB

    // XCD swizzle: block id -> (rb, tt) such that each XCD owns whole tt groups.
    int id = blockIdx.x;
    int rb, tt;
    if (n_tiles == 32) {
        int xcd  = id & 7;
        int slot = id >> 3;          // 0..255 within XCD
        rb = slot & 63;
        tt = xcd * 4 + (slot >> 6);  // 4 token-tiles per XCD
    } else {
        rb = id & 63;
        tt = id >> 6;
    }

    const int tid  = threadIdx.x;
    const int lane = tid & 63;
    const int wv   = tid >> 6;
    const int l15  = lane & 15;
    const int l4   = lane >> 4;
    const int tok0 = tt * TM;

    floatx4 acc[4][4];
    #pragma unroll
    for (int i = 0; i < 4; ++i)
        #pragma unroll
        for (int j = 0; j < 4; ++j)
            acc[i][j] = (floatx4){0.f, 0.f, 0.f, 0.f};

    for (int kb = 0; kb < KNZ; ++kb) {
        const int nz = rb * KNZ + kb;
        const int cb = col_idx[nz];
        const unsigned short* xsrc = xb + (size_t)tok0 * 4096 + (size_t)cb * 64;
        const unsigned short* wsrc = wb + (size_t)nz * 4096;

        __syncthreads();

        // Stage X tile: 256 rows x 64 bf16 = 32 KB -> 8 x 16B per thread.
        #pragma unroll
        for (int i = 0; i < 8; ++i) {
            int f   = i * NTHREADS + tid;   // 0..2047
            int row = f >> 3;               // 8 chunks of 8 bf16 per row
            int c8  = f & 7;
            short8 v = *(const short8*)(xsrc + (size_t)row * 4096 + c8 * 8);
            *(short8*)&Xs[row * XS_LD + c8 * 8] = v;
        }
        // Stage W block: 64x64 bf16 = 8 KB -> 2 x 16B per thread.
        #pragma unroll
        for (int i = 0; i < 2; ++i) {
            int f   = i * NTHREADS + tid;   // 0..511
            int row = f >> 3;
            int c8  = f & 7;
            short8 v = *(const short8*)(wsrc + row * 64 + c8 * 8);
            *(short8*)&Ws[row * WS_LD + c8 * 8] = v;
        }

        __syncthreads();

        #pragma unroll
        for (int ks = 0; ks < 2; ++ks) {
            const int k0 = ks * 32 + l4 * 8;
            short8 a[4], b[4];
            #pragma unroll
            for (int mt = 0; mt < 4; ++mt)
                a[mt] = *(const short8*)&Xs[(wv * 64 + mt * 16 + l15) * XS_LD + k0];
            #pragma unroll
            for (int nt = 0; nt < 4; ++nt)
                b[nt] = *(const short8*)&Ws[(nt * 16 + l15) * WS_LD + k0];
            #pragma unroll
            for (int mt = 0; mt < 4; ++mt)
                #pragma unroll
                for (int nt = 0; nt < 4; ++nt)
                    acc[mt][nt] = __builtin_amdgcn_mfma_f32_16x16x32_bf16(
                        a[mt], b[nt], acc[mt][nt], 0, 0, 0);
        }
    }

    // Epilogue: C/D layout col = lane&15, row = (lane>>4)*4 + reg.
    const int ocol0 = rb * 64;
    #pragma unroll
    for (int nt = 0; nt < 4; ++nt) {
        const int col = ocol0 + nt * 16 + l15;
        const float bv = bias[col];
        #pragma unroll
        for (int mt = 0; mt < 4; ++mt) {
            const size_t trow = (size_t)tok0 + wv * 64 + mt * 16 + l4 * 4;
            float* op = out + trow * 4096 + col;
            #pragma unroll
            for (int r = 0; r < 4; ++r)
                op[(size_t)r * 4096] = acc[mt][nt][r] + bv;
        }
    }
}

// ---- Fallback (round-1 fp32 kernel) if ws too small ----
__global__ __launch_bounds__(NTHREADS)
void bsl_mfma_f32_kernel(const float* __restrict__ x,
                         const float* __restrict__ w,
                         const float* __restrict__ bias,
                         const int* __restrict__ col_idx,
                         float* __restrict__ out)
{
    __shared__ unsigned short Xs[TM * XS_LD];
    __shared__ unsigned short Ws[64 * WS_LD];
    const int rb = blockIdx.x, tt = blockIdx.y;
    const int tid = threadIdx.x, lane = tid & 63, wv = tid >> 6;
    const int l15 = lane & 15, l4 = lane >> 4, tok0 = tt * TM;
    floatx4 acc[4][4];
    #pragma unroll
    for (int i = 0; i < 4; ++i)
        #pragma unroll
        for (int j = 0; j < 4; ++j) acc[i][j] = (floatx4){0.f,0.f,0.f,0.f};
    for (int kb = 0; kb < KNZ; ++kb) {
        const int nz = rb * KNZ + kb;
        const int cb = col_idx[nz];
        const float* xsrc = x + (size_t)tok0 * 4096 + (size_t)cb * 64;
        const float* wsrc = w + (size_t)nz * 4096;
        __syncthreads();
        #pragma unroll
        for (int i = 0; i < 16; ++i) {
            int f = i * NTHREADS + tid, row = f >> 4, c4 = f & 15;
            floatx4 v = *(const floatx4*)(xsrc + (size_t)row * 4096 + c4 * 4);
            ushort4 p; p.x=f2bf(v.x); p.y=f2bf(v.y); p.z=f2bf(v.z); p.w=f2bf(v.w);
            *(ushort4*)&Xs[row * XS_LD + c4 * 4] = p;
        }
        #pragma unroll
        for (int i = 0; i < 4; ++i) {
            int f = i * NTHREADS + tid, row = f >> 4, c4 = f & 15;
            floatx4 v = *(const floatx4*)(wsrc + row * 64 + c4 * 4);
            ushort4 p; p.x=f2bf(v.x); p.y=f2bf(v.y); p.z=f2bf(v.z); p.w=f2bf(v.w);
            *(ushort4*)&Ws[row * WS_LD + c4 * 4] = p;
        }
        __syncthreads();
        #pragma unroll
        for (int ks = 0; ks < 2; ++ks) {
            const int k0 = ks * 32 + l4 * 8;
            short8 a[4], b[4];
            #pragma unroll
            for (int mt = 0; mt < 4; ++mt)
                a[mt] = *(const short8*)&Xs[(wv*64 + mt*16 + l15) * XS_LD + k0];
            #pragma unroll
            for (int nt = 0; nt < 4; ++nt)
                b[nt] = *(const short8*)&Ws[(nt*16 + l15) * WS_LD + k0];
            #pragma unroll
            for (int mt = 0; mt < 4; ++mt)
                #pragma unroll
                for (int nt = 0; nt < 4; ++nt)
                    acc[mt][nt] = __builtin_amdgcn_mfma_f32_16x16x32_bf16(
                        a[mt], b[nt], acc[mt][nt], 0, 0, 0);
        }
    }
    const int ocol0 = rb * 64;
    #pragma unroll
    for (int nt = 0; nt < 4; ++nt) {
        const int col = ocol0 + nt * 16 + l15;
        const float bv = bias[col];
        #pragma unroll
        for (int mt = 0; mt < 4; ++mt) {
            const size_t trow = (size_t)tok0 + wv * 64 + mt * 16 + l4 * 4;
            float* op = out + trow * 4096 + col;
            #pragma unroll
            for (int r = 0; r < 4; ++r)
                op[(size_t)r * 4096] = acc[mt][nt][r] + bv;
        }
    }
}

extern "C" void kernel_launch(void* const* d_in, const int* in_sizes, int n_in,
                              void* d_out, int out_size, void* d_ws, size_t ws_size,
                              hipStream_t stream) {
    const float* x       = (const float*)d_in[0];
    const float* w       = (const float*)d_in[1];
    const float* bias    = (const float*)d_in[2];
    const int*   col_idx = (const int*)d_in[4];
    float*       out     = (float*)d_out;

    const int n_x = in_sizes[0];               // 33554432
    const int n_w = in_sizes[1];               // 4194304
    const int n_tok = n_x / 4096;              // 8192
    const size_t need = (size_t)(n_x + n_w) * 2;

    if (ws_size >= need) {
        unsigned short* xb = (unsigned short*)d_ws;
        unsigned short* wb = xb + n_x;
        int n_x8 = n_x / 8, n_w8 = n_w / 8;
        int total = n_x8 + n_w8;
        cvt_kernel<<<(total + NTHREADS - 1) / NTHREADS, NTHREADS, 0, stream>>>(
            x, w, xb, wb, n_x8, n_w8);
        int n_tiles = n_tok / TM;
        bsl_mfma_bf16_kernel<<<64 * n_tiles, NTHREADS, 0, stream>>>(
            xb, wb, bias, col_idx, out, n_tiles);
    } else {
        dim3 grid(64, n_tok / TM);
        bsl_mfma_f32_kernel<<<grid, NTHREADS, 0, stream>>>(x, w, bias, col_idx, out);
    }
}

// Round 3
// 338.126 us; speedup vs baseline: 1.4483x; 1.0293x over previous
//
#include <hip/hip_runtime.h>
#include <hip/hip_bf16.h>

// BlockSparseLinear: y = x @ W^T + b
// Round 3: GEMM staging via __builtin_amdgcn_global_load_lds (16B DMA, no VGPR
// round-trip). LDS is unpadded (required: DMA dest = wave-uniform base + lane*16);
// bank conflicts on fragment reads avoided with an XOR chunk swizzle
// (sw = c8 ^ (row&7)) applied by permuting the per-lane GLOBAL source address.
// bf16 pre-convert pass (round 2) retained: keeps GEMM fetch at ~200 MB.

#define NTHREADS 256
#define TM 256          // tokens per workgroup tile
#define KNZ 16          // nonzero col-blocks per row-block

typedef __attribute__((ext_vector_type(8))) short short8;    // bf16 x8 (16 B)
typedef __attribute__((ext_vector_type(4))) float floatx4;

__device__ __forceinline__ unsigned short f2bf(float f) {
    unsigned u = __float_as_uint(f);
    u += 0x7fffu + ((u >> 16) & 1u);
    return (unsigned short)(u >> 16);
}

// async 16B global -> LDS DMA; lds base must be wave-uniform, dest = base + lane*16
__device__ __forceinline__ void gl_lds_16(const void* g, void* l) {
    __builtin_amdgcn_global_load_lds(
        (const __attribute__((address_space(1))) unsigned int*)g,
        (__attribute__((address_space(3))) unsigned int*)l,
        16, 0, 0);
}

// ---- Kernel 1: fp32 -> bf16 conversion (x then w) ----
__global__ __launch_bounds__(NTHREADS)
void cvt_kernel(const float* __restrict__ x, const float* __restrict__ w,
                unsigned short* __restrict__ xb, unsigned short* __restrict__ wb,
                int n_x8, int n_w8)
{
    int g = blockIdx.x * NTHREADS + threadIdx.x;
    const float* src;
    unsigned short* dst;
    if (g < n_x8) { src = x + (size_t)g * 8; dst = xb + (size_t)g * 8; }
    else {
        int h = g - n_x8;
        if (h >= n_w8) return;
        src = w + (size_t)h * 8; dst = wb + (size_t)h * 8;
    }
    floatx4 v0 = *(const floatx4*)(src);
    floatx4 v1 = *(const floatx4*)(src + 4);
    union { ushort4 u4[2]; short8 s8; } p;
    p.u4[0].x = f2bf(v0.x); p.u4[0].y = f2bf(v0.y);
    p.u4[0].z = f2bf(v0.z); p.u4[0].w = f2bf(v0.w);
    p.u4[1].x = f2bf(v1.x); p.u4[1].y = f2bf(v1.y);
    p.u4[1].z = f2bf(v1.z); p.u4[1].w = f2bf(v1.w);
    *(short8*)dst = p.s8;
}

// ---- Kernel 2: bf16 MFMA GEMM with async LDS staging ----
__global__ __launch_bounds__(NTHREADS)
void bsl_mfma_bf16_kernel(const unsigned short* __restrict__ xb,
                          const unsigned short* __restrict__ wb,
                          const float* __restrict__ bias,
                          const int* __restrict__ col_idx,
                          float* __restrict__ out,
                          int n_tiles)
{
    // Unpadded: row stride 64 bf16 = 128 B. Chunk (16B) position is XOR-swizzled.
    __shared__ unsigned short Xs[TM * 64];   // 32 KB
    __shared__ unsigned short Ws[64 * 64];   // 8 KB

    // XCD swizzle: consecutive block ids round-robin across 8 XCDs; give each
    // XCD whole token-tile groups so its 2 MB x-slab stays hot in L2/L3.
    int id = blockIdx.x;
    int rb, tt;
    if (n_tiles == 32) {
        int xcd  = id & 7;
        int slot = id >> 3;          // 0..255 within XCD
        rb = slot & 63;
        tt = xcd * 4 + (slot >> 6);
    } else {
        rb = id & 63;
        tt = id >> 6;
    }

    const int tid  = threadIdx.x;
    const int lane = tid & 63;
    const int wv   = tid >> 6;
    const int l15  = lane & 15;
    const int l4   = lane >> 4;
    const int tok0 = tt * TM;
    const int lr   = lane >> 3;      // 0..7: row within a DMA wave-load
    const int lc   = lane & 7;       // 0..7: swizzled chunk slot

    floatx4 acc[4][4];
    #pragma unroll
    for (int i = 0; i < 4; ++i)
        #pragma unroll
        for (int j = 0; j < 4; ++j)
            acc[i][j] = (floatx4){0.f, 0.f, 0.f, 0.f};

    for (int kb = 0; kb < KNZ; ++kb) {
        const int nz = rb * KNZ + kb;
        const int cb = col_idx[nz];
        const unsigned short* xsrc = xb + (size_t)tok0 * 4096 + (size_t)cb * 64;
        const unsigned short* wsrc = wb + (size_t)nz * 4096;

        __syncthreads();   // previous compute done before overwriting LDS

        // X: 256 rows x 8 chunks = 32 wave-loads of 1 KB; wave wv does 8.
        // LDS slot s = L*64 + lane holds global chunk c8 = (lane&7) ^ (row&7).
        #pragma unroll
        for (int j = 0; j < 8; ++j) {
            int L   = wv * 8 + j;
            int row = L * 8 + lr;
            int c8  = lc ^ (row & 7);
            gl_lds_16(xsrc + (size_t)row * 4096 + c8 * 8, &Xs[L * 512]);
        }
        // W: 64 rows x 8 chunks = 8 wave-loads; wave wv does 2.
        #pragma unroll
        for (int j = 0; j < 2; ++j) {
            int L   = wv * 2 + j;
            int row = L * 8 + lr;
            int c8  = lc ^ (row & 7);
            gl_lds_16(wsrc + row * 64 + c8 * 8, &Ws[L * 512]);
        }

        __syncthreads();   // drains vmcnt -> DMA complete, staging visible

        // Compute: K=64 as two k-steps of 32. Chunk c8k = ks*4 + l4 lives at
        // swizzled offset (c8k ^ (row&7))*8; row&7 == l15&7 for all frags.
        #pragma unroll
        for (int ks = 0; ks < 2; ++ks) {
            const int sw8 = ((ks * 4 + l4) ^ (l15 & 7)) * 8;
            short8 a[4], b[4];
            #pragma unroll
            for (int mt = 0; mt < 4; ++mt)
                a[mt] = *(const short8*)&Xs[(wv * 64 + mt * 16 + l15) * 64 + sw8];
            #pragma unroll
            for (int nt = 0; nt < 4; ++nt)
                b[nt] = *(const short8*)&Ws[(nt * 16 + l15) * 64 + sw8];
            #pragma unroll
            for (int mt = 0; mt < 4; ++mt)
                #pragma unroll
                for (int nt = 0; nt < 4; ++nt)
                    acc[mt][nt] = __builtin_amdgcn_mfma_f32_16x16x32_bf16(
                        a[mt], b[nt], acc[mt][nt], 0, 0, 0);
        }
    }

    // Epilogue: C/D layout col = lane&15, row = (lane>>4)*4 + reg.
    const int ocol0 = rb * 64;
    #pragma unroll
    for (int nt = 0; nt < 4; ++nt) {
        const int col = ocol0 + nt * 16 + l15;
        const float bv = bias[col];
        #pragma unroll
        for (int mt = 0; mt < 4; ++mt) {
            const size_t trow = (size_t)tok0 + wv * 64 + mt * 16 + l4 * 4;
            float* op = out + trow * 4096 + col;
            #pragma unroll
            for (int r = 0; r < 4; ++r)
                op[(size_t)r * 4096] = acc[mt][nt][r] + bv;
        }
    }
}

// ---- Fallback (fp32 direct) if ws too small ----
#define XS_LD 72
#define WS_LD 72
__global__ __launch_bounds__(NTHREADS)
void bsl_mfma_f32_kernel(const float* __restrict__ x,
                         const float* __restrict__ w,
                         const float* __restrict__ bias,
                         const int* __restrict__ col_idx,
                         float* __restrict__ out)
{
    __shared__ unsigned short Xs[TM * XS_LD];
    __shared__ unsigned short Ws[64 * WS_LD];
    const int rb = blockIdx.x, tt = blockIdx.y;
    const int tid = threadIdx.x, lane = tid & 63, wv = tid >> 6;
    const int l15 = lane & 15, l4 = lane >> 4, tok0 = tt * TM;
    floatx4 acc[4][4];
    #pragma unroll
    for (int i = 0; i < 4; ++i)
        #pragma unroll
        for (int j = 0; j < 4; ++j) acc[i][j] = (floatx4){0.f,0.f,0.f,0.f};
    for (int kb = 0; kb < KNZ; ++kb) {
        const int nz = rb * KNZ + kb;
        const int cb = col_idx[nz];
        const float* xsrc = x + (size_t)tok0 * 4096 + (size_t)cb * 64;
        const float* wsrc = w + (size_t)nz * 4096;
        __syncthreads();
        #pragma unroll
        for (int i = 0; i < 16; ++i) {
            int f = i * NTHREADS + tid, row = f >> 4, c4 = f & 15;
            floatx4 v = *(const floatx4*)(xsrc + (size_t)row * 4096 + c4 * 4);
            ushort4 p; p.x=f2bf(v.x); p.y=f2bf(v.y); p.z=f2bf(v.z); p.w=f2bf(v.w);
            *(ushort4*)&Xs[row * XS_LD + c4 * 4] = p;
        }
        #pragma unroll
        for (int i = 0; i < 4; ++i) {
            int f = i * NTHREADS + tid, row = f >> 4, c4 = f & 15;
            floatx4 v = *(const floatx4*)(wsrc + row * 64 + c4 * 4);
            ushort4 p; p.x=f2bf(v.x); p.y=f2bf(v.y); p.z=f2bf(v.z); p.w=f2bf(v.w);
            *(ushort4*)&Ws[row * WS_LD + c4 * 4] = p;
        }
        __syncthreads();
        #pragma unroll
        for (int ks = 0; ks < 2; ++ks) {
            const int k0 = ks * 32 + l4 * 8;
            short8 a[4], b[4];
            #pragma unroll
            for (int mt = 0; mt < 4; ++mt)
                a[mt] = *(const short8*)&Xs[(wv*64 + mt*16 + l15) * XS_LD + k0];
            #pragma unroll
            for (int nt = 0; nt < 4; ++nt)
                b[nt] = *(const short8*)&Ws[(nt*16 + l15) * WS_LD + k0];
            #pragma unroll
            for (int mt = 0; mt < 4; ++mt)
                #pragma unroll
                for (int nt = 0; nt < 4; ++nt)
                    acc[mt][nt] = __builtin_amdgcn_mfma_f32_16x16x32_bf16(
                        a[mt], b[nt], acc[mt][nt], 0, 0, 0);
        }
    }
    const int ocol0 = rb * 64;
    #pragma unroll
    for (int nt = 0; nt < 4; ++nt) {
        const int col = ocol0 + nt * 16 + l15;
        const float bv = bias[col];
        #pragma unroll
        for (int mt = 0; mt < 4; ++mt) {
            const size_t trow = (size_t)tok0 + wv * 64 + mt * 16 + l4 * 4;
            float* op = out + trow * 4096 + col;
            #pragma unroll
            for (int r = 0; r < 4; ++r)
                op[(size_t)r * 4096] = acc[mt][nt][r] + bv;
        }
    }
}

extern "C" void kernel_launch(void* const* d_in, const int* in_sizes, int n_in,
                              void* d_out, int out_size, void* d_ws, size_t ws_size,
                              hipStream_t stream) {
    const float* x       = (const float*)d_in[0];
    const float* w       = (const float*)d_in[1];
    const float* bias    = (const float*)d_in[2];
    const int*   col_idx = (const int*)d_in[4];
    float*       out     = (float*)d_out;

    const int n_x = in_sizes[0];
    const int n_w = in_sizes[1];
    const int n_tok = n_x / 4096;
    const size_t need = (size_t)(n_x + n_w) * 2;

    if (ws_size >= need) {
        unsigned short* xb = (unsigned short*)d_ws;
        unsigned short* wb = xb + n_x;
        int n_x8 = n_x / 8, n_w8 = n_w / 8;
        int total = n_x8 + n_w8;
        cvt_kernel<<<(total + NTHREADS - 1) / NTHREADS, NTHREADS, 0, stream>>>(
            x, w, xb, wb, n_x8, n_w8);
        int n_tiles = n_tok / TM;
        bsl_mfma_bf16_kernel<<<64 * n_tiles, NTHREADS, 0, stream>>>(
            xb, wb, bias, col_idx, out, n_tiles);
    } else {
        dim3 grid(64, n_tok / TM);
        bsl_mfma_f32_kernel<<<grid, NTHREADS, 0, stream>>>(x, w, bias, col_idx, out);
    }
}